// Round 1
// baseline (324.989 us; speedup 1.0000x reference)
//
#include <hip/hip_runtime.h>
#include <stdint.h>

// ---------------- problem dims ----------------
#define B_DIM 64
#define P_DIM 225
#define K_DIM 16
#define D_DIM 640
#define M_REAL (B_DIM * P_DIM)   // 14400 query rows
#define N_REAL (K_DIM * P_DIM)   // 3600 reference rows

// ---------------- GEMM tiling ----------------
#define BM 128
#define BN 128
#define BKT 32
#define MTILES 113               // ceil(14400/128) -> Mpad 14464
#define NTILES 29                // ceil(3600/128)  -> Npad 3712
#define MPAD (MTILES * BM)
#define NPAD (NTILES * BN)

typedef __bf16 bf16x8 __attribute__((ext_vector_type(8)));
typedef float f32x4 __attribute__((ext_vector_type(4)));

// ---------------- helpers ----------------
__device__ __forceinline__ unsigned short f2bf(float f) {
  union { float f; unsigned u; } v; v.f = f;
  unsigned u = v.u;
  return (unsigned short)((u + 0x7FFFu + ((u >> 16) & 1u)) >> 16);  // RNE
}

// monotone float -> uint key (order-preserving), for atomicMax on floats
__device__ __forceinline__ unsigned f2key(float f) {
  union { float f; unsigned u; } v; v.f = f;
  unsigned u = v.u;
  return (u & 0x80000000u) ? ~u : (u | 0x80000000u);
}
__device__ __forceinline__ float key2f(unsigned k) {
  unsigned b = (k & 0x80000000u) ? (k ^ 0x80000000u) : ~k;
  union { unsigned u; float f; } v; v.u = b;
  return v.f;
}

__device__ __forceinline__ void gl_lds16(const void* g, void* l) {
  __builtin_amdgcn_global_load_lds(
      (const __attribute__((address_space(1))) void*)g,
      (__attribute__((address_space(3))) void*)l,
      16, 0, 0);
}

// ---------------- stage q: qinv + raw bf16 cast (rows >= M_REAL zero) ----------------
__global__ __launch_bounds__(256) void stage_q_kernel(
    const float* __restrict__ q, unsigned short* __restrict__ qb,
    float* __restrict__ qinv) {
  int row = blockIdx.x * 4 + (threadIdx.x >> 6);
  int lane = threadIdx.x & 63;
  unsigned short* dst = qb + (long)row * D_DIM;
  if (row >= M_REAL) {
#pragma unroll
    for (int i = 0; i < 10; i++) dst[i * 64 + lane] = 0;
    return;
  }
  const float* src = q + (long)row * D_DIM;
  float v[10];
  float ss = 0.f;
#pragma unroll
  for (int i = 0; i < 10; i++) { v[i] = src[i * 64 + lane]; ss += v[i] * v[i]; }
#pragma unroll
  for (int off = 32; off > 0; off >>= 1) ss += __shfl_xor(ss, off);
  float inv = 1.f / (sqrtf(ss) + 1e-6f);
  if (lane == 0) qinv[row] = inv;
#pragma unroll
  for (int i = 0; i < 10; i++) dst[i * 64 + lane] = f2bf(v[i]);
}

// ---------------- stage r: L2-normalize rows, bf16 cast (rows >= N_REAL zero) ----------------
__global__ __launch_bounds__(256) void stage_r_kernel(
    const float* __restrict__ r, unsigned short* __restrict__ rb) {
  int row = blockIdx.x * 4 + (threadIdx.x >> 6);
  int lane = threadIdx.x & 63;
  unsigned short* dst = rb + (long)row * D_DIM;
  if (row >= N_REAL) {
#pragma unroll
    for (int i = 0; i < 10; i++) dst[i * 64 + lane] = 0;
    return;
  }
  const float* src = r + (long)row * D_DIM;
  float v[10];
  float ss = 0.f;
#pragma unroll
  for (int i = 0; i < 10; i++) { v[i] = src[i * 64 + lane]; ss += v[i] * v[i]; }
#pragma unroll
  for (int off = 32; off > 0; off >>= 1) ss += __shfl_xor(ss, off);
  float sc = 1.f / (sqrtf(ss) + 1e-6f);
#pragma unroll
  for (int i = 0; i < 10; i++) dst[i * 64 + lane] = f2bf(v[i] * sc);
}

// ---------------- fused bf16 MFMA GEMM + row-max (m97 structure) ----------------
// C[m][n] = sum_k Qb[m][k] * Rb[n][k]; epilogue: atomicMax per row over n.
__global__ __launch_bounds__(256) void sim_max_kernel(
    const unsigned short* __restrict__ Qb,
    const unsigned short* __restrict__ Rb,
    unsigned* __restrict__ rowmax) {
  __shared__ __attribute__((aligned(16))) unsigned short As[BM * BKT];  // 8 KB
  __shared__ __attribute__((aligned(16))) unsigned short Bs[BN * BKT];  // 8 KB

  const int tid = threadIdx.x;
  const int wave = tid >> 6, lane = tid & 63;
  const int wr = wave >> 1, wc = wave & 1;
  const int bn = blockIdx.x % NTILES;
  const int bm = blockIdx.x / NTILES;
  const int q = lane >> 4, m0 = lane & 15;

  // staging geometry: chunk c of wave -> LDS bytes [((wave*2+c)*64+lane)*16, +16)
  const int fA0 = ((wave * 2 + 0) * 64 + lane) * 16;
  const int fA1 = ((wave * 2 + 1) * 64 + lane) * 16;
  const int rowA0 = fA0 >> 6, colA0 = (fA0 & 63) >> 1;  // row stride 32 bf16 = 64 B
  const int rowA1 = fA1 >> 6, colA1 = (fA1 & 63) >> 1;

  const int aBase = bm * BM;
  const int bBase = bn * BN;

  f32x4 zero = {0.f, 0.f, 0.f, 0.f};
  f32x4 acc[4][4];
#pragma unroll
  for (int i = 0; i < 4; i++)
#pragma unroll
    for (int j = 0; j < 4; j++) acc[i][j] = zero;

  for (int k0 = 0; k0 < D_DIM; k0 += BKT) {
    gl_lds16(Qb + (aBase + rowA0) * D_DIM + k0 + colA0, &As[fA0 / 2]);
    gl_lds16(Qb + (aBase + rowA1) * D_DIM + k0 + colA1, &As[fA1 / 2]);
    gl_lds16(Rb + (bBase + rowA0) * D_DIM + k0 + colA0, &Bs[fA0 / 2]);
    gl_lds16(Rb + (bBase + rowA1) * D_DIM + k0 + colA1, &Bs[fA1 / 2]);
    __syncthreads();  // drains vmcnt -> LDS tiles ready

    bf16x8 af[4], bfr[4];
#pragma unroll
    for (int mi = 0; mi < 4; mi++)
      af[mi] = *(const bf16x8*)&As[(wr * 64 + mi * 16 + m0) * BKT + q * 8];
#pragma unroll
    for (int ni = 0; ni < 4; ni++)
      bfr[ni] = *(const bf16x8*)&Bs[(wc * 64 + ni * 16 + m0) * BKT + q * 8];
#pragma unroll
    for (int mi = 0; mi < 4; mi++)
#pragma unroll
      for (int ni = 0; ni < 4; ni++)
        acc[mi][ni] = __builtin_amdgcn_mfma_f32_16x16x32_bf16(
            af[mi], bfr[ni], acc[mi][ni], 0, 0, 0);
    __syncthreads();  // protect LDS before next-iter overwrite
  }

  // epilogue: per-row max over this block's 128 columns, then global atomicMax
  const int colBase = bn * BN + wc * 64;
#pragma unroll
  for (int mi = 0; mi < 4; mi++) {
    float rmax[4] = {-3.0e38f, -3.0e38f, -3.0e38f, -3.0e38f};
#pragma unroll
    for (int ni = 0; ni < 4; ni++) {
      bool valid = (colBase + ni * 16 + m0) < N_REAL;
#pragma unroll
      for (int r = 0; r < 4; r++) {
        float v = valid ? acc[mi][ni][r] : -3.0e38f;
        rmax[r] = fmaxf(rmax[r], v);
      }
    }
#pragma unroll
    for (int r = 0; r < 4; r++) {
      float v = rmax[r];
      v = fmaxf(v, __shfl_xor(v, 1));
      v = fmaxf(v, __shfl_xor(v, 2));
      v = fmaxf(v, __shfl_xor(v, 4));
      v = fmaxf(v, __shfl_xor(v, 8));
      rmax[r] = v;
    }
    if (m0 == 0) {
      int row = bm * BM + wr * 64 + mi * 16 + q * 4;
#pragma unroll
      for (int r = 0; r < 4; r++)
        atomicMax(&rowmax[row + r], f2key(rmax[r]));
    }
  }
}

// ---------------- adapter: h1 = relu(r_img @ w1) ----------------
__global__ __launch_bounds__(192) void adapter1_kernel(
    const float* __restrict__ r_img, const float* __restrict__ w1,
    float* __restrict__ h1) {
  int k = blockIdx.x, j = threadIdx.x;
  if (j >= 160) return;
  const float* rk = r_img + k * D_DIM;
  float a0 = 0.f, a1 = 0.f, a2 = 0.f, a3 = 0.f;
  for (int d = 0; d < D_DIM; d += 4) {
    a0 += rk[d + 0] * w1[(d + 0) * 160 + j];
    a1 += rk[d + 1] * w1[(d + 1) * 160 + j];
    a2 += rk[d + 2] * w1[(d + 2) * 160 + j];
    a3 += rk[d + 3] * w1[(d + 3) * 160 + j];
  }
  h1[k * 160 + j] = fmaxf(a0 + a1 + a2 + a3, 0.f);
}

// ---------------- adapter: favg[d] = mean_k relu(h1 @ w2) ----------------
__global__ __launch_bounds__(64) void adapter2_kernel(
    const float* __restrict__ h1, const float* __restrict__ w2,
    float* __restrict__ favg) {
  int d = blockIdx.x * 64 + threadIdx.x;  // 10 blocks x 64 = 640
  float a[K_DIM];
#pragma unroll
  for (int k = 0; k < K_DIM; k++) a[k] = 0.f;
  for (int j = 0; j < 160; j++) {
    float w = w2[j * D_DIM + d];
#pragma unroll
    for (int k = 0; k < K_DIM; k++) a[k] += h1[k * 160 + j] * w;
  }
  float s = 0.f;
#pragma unroll
  for (int k = 0; k < K_DIM; k++) s += fmaxf(a[k], 0.f);
  favg[d] = s * (1.f / 16.f);
}

// ---------------- s_ref head (on q_img - favg) ----------------
__global__ __launch_bounds__(128) void head_ref_kernel(
    const float* __restrict__ q_img, const float* __restrict__ favg,
    const float* __restrict__ w1, const float* __restrict__ b1,
    const float* __restrict__ g2, const float* __restrict__ be2,
    const float* __restrict__ w2, const float* __restrict__ b2,
    const float* __restrict__ g3, const float* __restrict__ be3,
    const float* __restrict__ w3, const float* __restrict__ b3,
    float* __restrict__ sref) {
  int b = blockIdx.x, t = threadIdx.x;
  __shared__ float x[D_DIM];
  __shared__ float h1s[128];
  __shared__ float h2s[64];
  for (int d = t; d < D_DIM; d += 128) x[d] = q_img[b * D_DIM + d] - favg[d];
  __syncthreads();
  {
    float a0 = b1[t], a1 = 0.f, a2 = 0.f, a3 = 0.f;
    for (int d = 0; d < D_DIM; d += 4) {
      a0 += x[d + 0] * w1[(d + 0) * 128 + t];
      a1 += x[d + 1] * w1[(d + 1) * 128 + t];
      a2 += x[d + 2] * w1[(d + 2) * 128 + t];
      a3 += x[d + 3] * w1[(d + 3) * 128 + t];
    }
    float a = a0 + a1 + a2 + a3;
    h1s[t] = fmaxf(a, 0.f) * g2[t] + be2[t];
  }
  __syncthreads();
  if (t < 64) {
    float a = b2[t];
    for (int j = 0; j < 128; j++) a += h1s[j] * w2[j * 64 + t];
    h2s[t] = fmaxf(a, 0.f) * g3[t] + be3[t];
  }
  __syncthreads();
  if (t < 64) {
    float p = h2s[t] * w3[t];
    p += __shfl_xor(p, 32); p += __shfl_xor(p, 16); p += __shfl_xor(p, 8);
    p += __shfl_xor(p, 4);  p += __shfl_xor(p, 2);  p += __shfl_xor(p, 1);
    if (t == 0) sref[b] = 1.f / (1.f + expf(-(p + b3[0])));
  }
}

// ---------------- amap + s_map head + final score ----------------
__global__ __launch_bounds__(256) void head_map_kernel(
    const unsigned* __restrict__ rowmax, const float* __restrict__ qinv,
    const float* __restrict__ sref,
    const float* __restrict__ w1, const float* __restrict__ b1,
    const float* __restrict__ g2, const float* __restrict__ be2,
    const float* __restrict__ w2, const float* __restrict__ b2,
    const float* __restrict__ g3, const float* __restrict__ be3,
    const float* __restrict__ w3, const float* __restrict__ b3,
    float* __restrict__ out) {
  int b = blockIdx.x, t = threadIdx.x;
  __shared__ float amap[P_DIM];
  __shared__ float red[256];
  __shared__ float h1s[128];
  __shared__ float h2s[64];
  float av = 0.f;
  if (t < P_DIM) {
    int row = b * P_DIM + t;
    float mx = key2f(rowmax[row]);
    av = 0.5f * (1.f - mx * qinv[row]);
    amap[t] = av;
  }
  red[t] = av;
  __syncthreads();
  for (int s = 128; s > 0; s >>= 1) {
    if (t < s) red[t] += red[t + s];
    __syncthreads();
  }
  if (t < 128) {
    float a0 = b1[t], a1 = 0.f, a2 = 0.f;
    for (int p = 0; p < P_DIM; p += 3) {  // 225 = 75*3
      a0 += amap[p + 0] * w1[(p + 0) * 128 + t];
      a1 += amap[p + 1] * w1[(p + 1) * 128 + t];
      a2 += amap[p + 2] * w1[(p + 2) * 128 + t];
    }
    float a = a0 + a1 + a2;
    h1s[t] = fmaxf(a, 0.f) * g2[t] + be2[t];
  }
  __syncthreads();
  if (t < 64) {
    float a = b2[t];
    for (int j = 0; j < 128; j++) a += h1s[j] * w2[j * 64 + t];
    h2s[t] = fmaxf(a, 0.f) * g3[t] + be3[t];
  }
  __syncthreads();
  if (t < 64) {
    float p = h2s[t] * w3[t];
    p += __shfl_xor(p, 32); p += __shfl_xor(p, 16); p += __shfl_xor(p, 8);
    p += __shfl_xor(p, 4);  p += __shfl_xor(p, 2);  p += __shfl_xor(p, 1);
    if (t == 0) {
      float smap = 1.f / (1.f + expf(-(p + b3[0])));
      float amean = red[0] * (1.f / 225.f);
      out[b] = 0.5f * (sref[b] + smap) + amean;
    }
  }
}

// ---------------- launch ----------------
extern "C" void kernel_launch(void* const* d_in, const int* in_sizes, int n_in,
                              void* d_out, int out_size, void* d_ws, size_t ws_size,
                              hipStream_t stream) {
  const float* q_patch = (const float*)d_in[0];
  const float* r_patch = (const float*)d_in[1];
  const float* q_img   = (const float*)d_in[2];
  const float* r_img   = (const float*)d_in[3];
  const float* adpt_w1 = (const float*)d_in[4];
  const float* adpt_w2 = (const float*)d_in[5];
  const float* dh_w1 = (const float*)d_in[6];
  const float* dh_b1 = (const float*)d_in[7];
  const float* dh_g2 = (const float*)d_in[8];
  const float* dh_be2 = (const float*)d_in[9];
  const float* dh_w2 = (const float*)d_in[10];
  const float* dh_b2 = (const float*)d_in[11];
  const float* dh_g3 = (const float*)d_in[12];
  const float* dh_be3 = (const float*)d_in[13];
  const float* dh_w3 = (const float*)d_in[14];
  const float* dh_b3 = (const float*)d_in[15];
  const float* dr_w1 = (const float*)d_in[16];
  const float* dr_b1 = (const float*)d_in[17];
  const float* dr_g2 = (const float*)d_in[18];
  const float* dr_be2 = (const float*)d_in[19];
  const float* dr_w2 = (const float*)d_in[20];
  const float* dr_b2 = (const float*)d_in[21];
  const float* dr_g3 = (const float*)d_in[22];
  const float* dr_be3 = (const float*)d_in[23];
  const float* dr_w3 = (const float*)d_in[24];
  const float* dr_b3 = (const float*)d_in[25];

  // ws layout (bytes)
  const size_t QB_BYTES = (size_t)MPAD * D_DIM * 2;      // 18,513,920
  const size_t RB_BYTES = (size_t)NPAD * D_DIM * 2;      //  4,751,360
  char* ws = (char*)d_ws;
  unsigned short* qb = (unsigned short*)(ws);
  unsigned short* rb = (unsigned short*)(ws + QB_BYTES);
  float* qinv        = (float*)(ws + QB_BYTES + RB_BYTES);
  unsigned* rowmax   = (unsigned*)(ws + QB_BYTES + RB_BYTES + (size_t)M_REAL * 4);
  float* h1a         = (float*)(ws + QB_BYTES + RB_BYTES + (size_t)M_REAL * 4 + (size_t)MPAD * 4);
  float* favg        = h1a + 16 * 160;
  float* sref        = favg + D_DIM;

  // rowmax keys: 0 is the minimum of the monotone encoding
  hipMemsetAsync(rowmax, 0, (size_t)MPAD * sizeof(unsigned), stream);

  stage_q_kernel<<<MPAD / 4, 256, 0, stream>>>(q_patch, qb, qinv);
  stage_r_kernel<<<NPAD / 4, 256, 0, stream>>>(r_patch, rb);
  sim_max_kernel<<<MTILES * NTILES, 256, 0, stream>>>(qb, rb, rowmax);

  adapter1_kernel<<<16, 192, 0, stream>>>(r_img, adpt_w1, h1a);
  adapter2_kernel<<<10, 64, 0, stream>>>(h1a, adpt_w2, favg);
  head_ref_kernel<<<64, 128, 0, stream>>>(q_img, favg, dr_w1, dr_b1, dr_g2, dr_be2,
                                          dr_w2, dr_b2, dr_g3, dr_be3, dr_w3, dr_b3, sref);
  head_map_kernel<<<64, 256, 0, stream>>>(rowmax, qinv, sref, dh_w1, dh_b1, dh_g2, dh_be2,
                                          dh_w2, dh_b2, dh_g3, dh_be3, dh_w3, dh_b3,
                                          (float*)d_out);
}